// Round 1
// baseline (38518.945 us; speedup 1.0000x reference)
//
#include <hip/hip_runtime.h>

#define BB 32
#define TT 512
#define SS 1024
#define HH 512
#define MM 16

// d_ws layout (bytes):
//   [0, 1024)            : unsigned slots[256]  (grid barrier)
//   [1024, 1024+64K)     : float ctx_st[32][512]
//   [66560, 66560+128K)  : float h_st[2][32][512]  (double buffered)

__device__ __forceinline__ float sigm(float z) { return 1.f / (1.f + __expf(-z)); }

__device__ __forceinline__ float ldg_agent(const float* p) {
  return __hip_atomic_load(p, __ATOMIC_RELAXED, __HIP_MEMORY_SCOPE_AGENT);
}
__device__ __forceinline__ void stg_agent(float* p, float v) {
  __hip_atomic_store(p, v, __ATOMIC_RELAXED, __HIP_MEMORY_SCOPE_AGENT);
}

__device__ __forceinline__ void gridbar(unsigned* slots, int bid, int tid, unsigned seq) {
  __threadfence_block();   // s_waitcnt: all my (scoped) stores retired to coherence point
  __syncthreads();         // whole block done
  if (tid == 0)
    __hip_atomic_store(&slots[bid], seq, __ATOMIC_RELEASE, __HIP_MEMORY_SCOPE_AGENT);
  if (tid < 256) {
    while (__hip_atomic_load(&slots[tid], __ATOMIC_RELAXED, __HIP_MEMORY_SCOPE_AGENT) < seq)
      __builtin_amdgcn_s_sleep(1);
  }
  __syncthreads();
  asm volatile("" ::: "memory");
}

__global__ void k_init(float* __restrict__ out_align, float* __restrict__ ctx_st,
                       float* __restrict__ h_st, unsigned* __restrict__ slots) {
  const size_t idx = (size_t)blockIdx.x * blockDim.x + threadIdx.x;
  const size_t stride = (size_t)gridDim.x * blockDim.x;
  const float4 z4 = make_float4(0.f, 0.f, 0.f, 0.f);
  float4* a4 = (float4*)out_align;
  const size_t n4 = (size_t)BB * TT * SS / 4;   // 4,194,304
  for (size_t i = idx; i < n4; i += stride) a4[i] = z4;
  if (idx < (size_t)BB * HH / 4) ((float4*)ctx_st)[idx] = z4;
  if (idx < (size_t)2 * BB * HH / 4) ((float4*)h_st)[idx] = z4;
  if (idx < 256) slots[idx] = 0u;
}

__launch_bounds__(512)
__global__ void k_main(const float* __restrict__ input, const float* __restrict__ memory,
                       const float* __restrict__ Wih, const float* __restrict__ Whh,
                       const float* __restrict__ bih, const float* __restrict__ bhh,
                       const float* __restrict__ Wg, const float* __restrict__ bgv,
                       float* __restrict__ out_ctx, float* __restrict__ out_align,
                       float* __restrict__ ctx_st, float* __restrict__ h_st,
                       unsigned* __restrict__ slots) {
  __shared__ float red[128 * 17 + 2];   // ks-split reduction
  __shared__ float gbuf[16 * 17];       // gates (16 b x 16 rows)
  __shared__ float bias_s[16];
  __shared__ float c_s[64];             // persistent cell state (16 b x 4 cols)
  __shared__ float h_s[HH];
  __shared__ float phi_s[48];
  __shared__ float alpha_s[MM], beta_s[MM], rbeta_s[MM], ksi_s[MM];
  __shared__ float w_s[SS];
  __shared__ int win_s[2];

  const int tid = threadIdx.x;
  const int bid = blockIdx.x;
  const int bhalf = bid & 1;        // which 16 batches
  const int jt = bid >> 1;          // 0..127 -> h-cols [4jt, 4jt+4)
  const int B0 = bhalf * 16;

  // GEMM thread coords
  const int ks = tid >> 4;          // 0..31 k-split
  const int rg = (tid >> 2) & 3;    // gate index (i,f,g,o)
  const int bg = tid & 3;           // batch group (4 b each)

  // fixed row pointers for this thread (4 rows: gate rg, cols 4jt..4jt+3)
  const float* wih_r[4];
  const float* whh_r[4];
#pragma unroll
  for (int j = 0; j < 4; ++j) {
    const int grow = rg * HH + jt * 4 + j;
    wih_r[j] = Wih + (size_t)grow * 1024;
    whh_r[j] = Whh + (size_t)grow * 512;
  }

  if (tid < 16) {
    const int g = tid >> 2, jc = tid & 3;
    const int grow = g * HH + jt * 4 + jc;
    bias_s[tid] = bih[grow] + bhh[grow];
  }
  if (tid < 64) c_s[tid] = 0.f;
  if (tid < MM) ksi_s[tid] = 0.f;
  __syncthreads();

  unsigned seq = 0;

  for (int t = 0; t < TT; ++t) {
    // ================= Phase A: gates GEMM + LSTM =================
    {
      float acc[4][4];
#pragma unroll
      for (int i2 = 0; i2 < 4; ++i2)
#pragma unroll
        for (int j = 0; j < 4; ++j) acc[i2][j] = 0.f;

      if (ks < 16) {
        // x_t region of W_ih (k in [0,512)) : plain cached loads from input
#pragma unroll
        for (int q = 0; q < 8; ++q) {
          const int k = ks * 32 + q * 4;
          float4 wv4[4];
#pragma unroll
          for (int j = 0; j < 4; ++j) wv4[j] = *(const float4*)(wih_r[j] + k);
#pragma unroll
          for (int i2 = 0; i2 < 4; ++i2) {
            const float4 xv = *(const float4*)(input + ((size_t)(B0 + bg * 4 + i2) * TT + t) * HH + k);
#pragma unroll
            for (int j = 0; j < 4; ++j)
              acc[i2][j] = fmaf(xv.x, wv4[j].x, fmaf(xv.y, wv4[j].y,
                           fmaf(xv.z, wv4[j].z, fmaf(xv.w, wv4[j].w, acc[i2][j]))));
          }
        }
      } else {
        // ctx region of W_ih (k in [512,1024)) : agent-scoped loads (LLC-coherent)
#pragma unroll
        for (int q = 0; q < 8; ++q) {
          const int k = ks * 32 + q * 4;
          const int cd = k - 512;
          float4 wv4[4];
#pragma unroll
          for (int j = 0; j < 4; ++j) wv4[j] = *(const float4*)(wih_r[j] + k);
#pragma unroll
          for (int i2 = 0; i2 < 4; ++i2) {
            const float* cp = ctx_st + (size_t)(B0 + bg * 4 + i2) * HH + cd;
            const float x0 = ldg_agent(cp + 0), x1 = ldg_agent(cp + 1);
            const float x2 = ldg_agent(cp + 2), x3 = ldg_agent(cp + 3);
#pragma unroll
            for (int j = 0; j < 4; ++j)
              acc[i2][j] = fmaf(x0, wv4[j].x, fmaf(x1, wv4[j].y,
                           fmaf(x2, wv4[j].z, fmaf(x3, wv4[j].w, acc[i2][j]))));
          }
        }
      }
      // h region (W_hh, K=512) : agent-scoped loads, double-buffered h
      {
        const float* hb = h_st + (size_t)(t & 1) * BB * HH;
#pragma unroll
        for (int q = 0; q < 4; ++q) {
          const int k2 = ks * 16 + q * 4;
          float4 wv4[4];
#pragma unroll
          for (int j = 0; j < 4; ++j) wv4[j] = *(const float4*)(whh_r[j] + k2);
#pragma unroll
          for (int i2 = 0; i2 < 4; ++i2) {
            const float* hp = hb + (size_t)(B0 + bg * 4 + i2) * HH + k2;
            const float x0 = ldg_agent(hp + 0), x1 = ldg_agent(hp + 1);
            const float x2 = ldg_agent(hp + 2), x3 = ldg_agent(hp + 3);
#pragma unroll
            for (int j = 0; j < 4; ++j)
              acc[i2][j] = fmaf(x0, wv4[j].x, fmaf(x1, wv4[j].y,
                           fmaf(x2, wv4[j].z, fmaf(x3, wv4[j].w, acc[i2][j]))));
          }
        }
      }
      // reduce over ks: in-wave (xor 16,32 combine 4 ks) then cross-wave via LDS
      const int lane = tid & 63, wvA = tid >> 6;
#pragma unroll
      for (int a = 0; a < 16; ++a) {
        float v = acc[a >> 2][a & 3];
        v += __shfl_xor(v, 16, 64);
        v += __shfl_xor(v, 32, 64);
        if (lane < 16) red[(wvA * 16 + lane) * 17 + a] = v;
      }
      __syncthreads();
      if (tid < 256) {
        const int tile = tid & 15, a = tid >> 4;
        float s2 = 0.f;
#pragma unroll
        for (int w2 = 0; w2 < 8; ++w2) s2 += red[(w2 * 16 + tile) * 17 + a];
        const int bgx = tile & 3, rgx = tile >> 2, ii = a >> 2, jj = a & 3;
        gbuf[(bgx * 4 + ii) * 17 + (rgx * 4 + jj)] = s2 + bias_s[rgx * 4 + jj];
      }
      __syncthreads();
      if (tid < 64) {
        const int bl = tid >> 2, jc = tid & 3;
        const float ig = gbuf[bl * 17 + jc];
        const float fg = gbuf[bl * 17 + 4 + jc];
        const float gg = gbuf[bl * 17 + 8 + jc];
        const float og = gbuf[bl * 17 + 12 + jc];
        float c = sigm(fg) * c_s[tid] + sigm(ig) * tanhf(gg);
        c_s[tid] = c;
        const float h = sigm(og) * tanhf(c);
        float* hw = h_st + (size_t)((t + 1) & 1) * BB * HH;
        stg_agent(hw + (size_t)(B0 + bl) * HH + jt * 4 + jc, h);
      }
    }
    gridbar(slots, bid, tid, ++seq);

    // ================= Phase B: phi, window, ctx (one block per batch) =================
    if (bid < BB) {
      const int b = bid;
      const float* hb = h_st + (size_t)((t + 1) & 1) * BB * HH;
      h_s[tid] = ldg_agent(hb + (size_t)b * HH + tid);
      __syncthreads();
      // phi = h @ Wg^T + bg : 8 waves x 6 rows
      {
        const int wv2 = tid >> 6, lane2 = tid & 63;
#pragma unroll
        for (int e = 0; e < 6; ++e) {
          const int r = wv2 * 6 + e;
          const float* wr = Wg + (size_t)r * HH + lane2;
          const float* hp = h_s + lane2;
          float p = 0.f;
#pragma unroll
          for (int j2 = 0; j2 < 8; ++j2) p = fmaf(hp[j2 * 64], wr[j2 * 64], p);
          p += __shfl_xor(p, 32, 64); p += __shfl_xor(p, 16, 64);
          p += __shfl_xor(p, 8, 64);  p += __shfl_xor(p, 4, 64);
          p += __shfl_xor(p, 2, 64);  p += __shfl_xor(p, 1, 64);
          if (lane2 == 0) phi_s[r] = p + bgv[r];
        }
      }
      __syncthreads();
      if (tid < MM) {
        ksi_s[tid] += __expf(phi_s[tid]);
        beta_s[tid] = __expf(phi_s[MM + tid]);
      }
      __syncthreads();
      if (tid == 0) {
        float mx = -1e30f;
        for (int m = 0; m < MM; ++m) mx = fmaxf(mx, phi_s[2 * MM + m]);
        float ssum = 0.f; float ev[MM];
        for (int m = 0; m < MM; ++m) { ev[m] = __expf(phi_s[2 * MM + m] - mx); ssum += ev[m]; }
        const float inv = 1.f / ssum;
        float lo = 1e30f, hi = -1e30f;
        for (int m = 0; m < MM; ++m) {
          alpha_s[m] = ev[m] * inv;
          rbeta_s[m] = 1.f / beta_s[m];
          const float dd = 13.f * beta_s[m] + 3.f;
          lo = fminf(lo, ksi_s[m] - dd);
          hi = fmaxf(hi, ksi_s[m] + dd);
        }
        int ilo = (int)floorf(lo); if (ilo < 0) ilo = 0; if (ilo > SS) ilo = SS;
        int ihi = (int)ceilf(hi) + 1; if (ihi > SS) ihi = SS; if (ihi < ilo) ihi = ilo;
        win_s[0] = ilo; win_s[1] = ihi;
      }
      __syncthreads();
      const int ilo = win_s[0], ihi = win_s[1];
      float* arow = out_align + ((size_t)b * TT + t) * SS;
      for (int s = ilo + tid; s < ihi; s += 512) {
        const float us = (float)s;
        float wsum = 0.f;
#pragma unroll
        for (int m = 0; m < MM; ++m) {
          const float rb = rbeta_s[m];
          const float z1 = (us + 1.5f - ksi_s[m]) * rb;
          const float z0 = (us + 0.5f - ksi_s[m]) * rb;
          wsum += alpha_s[m] * (sigm(z1) - sigm(z0));
        }
        w_s[s - ilo] = wsum;
        arow[s] = wsum;
      }
      __syncthreads();
      {
        const int d = tid;
        float acc3 = 0.f;
        const float* mrow = memory + ((size_t)b * SS + ilo) * HH + d;
        for (int s = ilo; s < ihi; ++s) { acc3 = fmaf(w_s[s - ilo], *mrow, acc3); mrow += HH; }
        stg_agent(ctx_st + (size_t)b * HH + d, acc3);
        const size_t o = ((size_t)b * TT + t) * HH + d;
        out_ctx[o] = acc3 + input[o];
      }
    }
    gridbar(slots, bid, tid, ++seq);
  }
}

extern "C" void kernel_launch(void* const* d_in, const int* in_sizes, int n_in,
                              void* d_out, int out_size, void* d_ws, size_t ws_size,
                              hipStream_t stream) {
  const float* input = (const float*)d_in[0];
  const float* memory = (const float*)d_in[1];
  const float* Wih = (const float*)d_in[2];
  const float* Whh = (const float*)d_in[3];
  const float* bih = (const float*)d_in[4];
  const float* bhh = (const float*)d_in[5];
  const float* Wg = (const float*)d_in[6];
  const float* bgv = (const float*)d_in[7];
  float* out_ctx = (float*)d_out;
  float* out_align = out_ctx + (size_t)BB * TT * HH;
  unsigned* slots = (unsigned*)d_ws;
  float* ctx_st = (float*)((char*)d_ws + 1024);
  float* h_st = (float*)((char*)d_ws + 1024 + (size_t)BB * HH * 4);

  k_init<<<dim3(2048), dim3(256), 0, stream>>>(out_align, ctx_st, h_st, slots);

  void* args[] = { (void*)&input, (void*)&memory, (void*)&Wih, (void*)&Whh,
                   (void*)&bih, (void*)&bhh, (void*)&Wg, (void*)&bgv,
                   (void*)&out_ctx, (void*)&out_align,
                   (void*)&ctx_st, (void*)&h_st, (void*)&slots };
  hipLaunchCooperativeKernel((void*)k_main, dim3(256), dim3(512), args, 0, stream);
}